// Round 7
// baseline (1566.011 us; speedup 1.0000x reference)
//
#include <hip/hip_runtime.h>
#include <hip/hip_bf16.h>

// B=2, S=2048 -> M=4096 tokens, K=4096, NN=11008, groupsize=128.
static constexpr int M  = 4096;
static constexpr int K  = 4096;
static constexpr int NN = 11008;

typedef _Float16 f16;
typedef _Float16 f16x2 __attribute__((ext_vector_type(2)));
typedef _Float16 f16x8 __attribute__((ext_vector_type(8)));
typedef float    f32x4 __attribute__((ext_vector_type(4)));

// ---------------------------------------------------------------------------
// GPTQ nibble j of an int32 covers k = 8r+j. The magic unpack emits the
// interleaved within-8 order [0,4,1,5,2,6,3,7]; all fp16 tensors (xp, h)
// and the LDS B tiles use this same permutation along their reduction dim.
// Numerics: (1024+w) and (1025+z) are exact fp16 integers; their difference
// is exact; single rounding at the final mul by s.
// ---------------------------------------------------------------------------
union dq_u { f16x2 h[4]; f16x8 v; };

__device__ __forceinline__ f16x8 dq8(unsigned q, f16x2 s2, f16x2 zc2) {
    dq_u u;
    unsigned t0 = ( q         & 0x000F000Fu) | 0x64006400u;
    unsigned t1 = ((q >> 4)   & 0x000F000Fu) | 0x64006400u;
    unsigned t2 = ((q >> 8)   & 0x000F000Fu) | 0x64006400u;
    unsigned t3 = ((q >> 12)  & 0x000F000Fu) | 0x64006400u;
    u.h[0] = (__builtin_bit_cast(f16x2, t0) - zc2) * s2;
    u.h[1] = (__builtin_bit_cast(f16x2, t1) - zc2) * s2;
    u.h[2] = (__builtin_bit_cast(f16x2, t2) - zc2) * s2;
    u.h[3] = (__builtin_bit_cast(f16x2, t3) - zc2) * s2;
    return u.v;
}

// async global -> LDS, 16 B/lane; LDS dest = wave-uniform base + lane*16.
__device__ __forceinline__ void gll16(const f16* g, f16* l) {
    __builtin_amdgcn_global_load_lds(
        (const __attribute__((address_space(1))) unsigned int*)g,
        (__attribute__((address_space(3))) unsigned int*)l,
        16, 0, 0);
}

// ---------------------------------------------------------------------------
// Pre-pass: x fp32 -> fp16, permuted within each 8 along K.
// ---------------------------------------------------------------------------
__global__ __launch_bounds__(256) void convert_x_kernel(
    const float* __restrict__ x, f16* __restrict__ xp)
{
    size_t i = ((size_t)blockIdx.x * 256 + threadIdx.x) * 8;
    float4 f0 = *(const float4*)(x + i);
    float4 f1 = *(const float4*)(x + i + 4);
    f16x8 v;
    v[0] = (f16)f0.x; v[1] = (f16)f1.x;
    v[2] = (f16)f0.y; v[3] = (f16)f1.y;
    v[4] = (f16)f0.z; v[5] = (f16)f1.z;
    v[6] = (f16)f0.w; v[7] = (f16)f1.w;
    *(f16x8*)(xp + i) = v;
}

// ---------------------------------------------------------------------------
// 256x256 GEMM with FUSED GPTQ dequant for the B operand.
// R2's verified 4-phase skeleton (1329 us, conflicts=0) kept intact:
//   P0: [issue B int4+scale loads for t+2]; ds A-mh0 + B-nh0; MFMA Q00; bar
//   P1: ds B-nh1;                                             MFMA Q01; bar
//   P2: ds A-mh1; [dq8 B(t+2) -> regs, VALU under MFMA];      MFMA Q10; bar
//   P3: [ds_write B(t+2)->LB[d]; gload_lds A(t+2)->LA[d]];    MFMA Q11;
//       lgkmcnt(0) (publish writes); bar
// Hazards: B(t+2) writes at P3 vs last B(d) read at P1 (2 bars apart);
// A(t+2) stage at P3 vs last A(d) read at P2 (1 bar). A(t+1) landing is
// guaranteed by the compiler's vmcnt wait before dq8 at P2 (all drained
// loads are >=1 tile old -> no self-drain; tail tiles use explicit vmcnt0).
// B dequant mapping: one int32 at k-chunk c of row r dequants to 8 f16 in
// the within-8 permuted order = exactly LDS row r, logical chunk c. Write
// addr applies the XOR swizzle (phys = chunk ^ (row&7)); reads unchanged.
// Combined gate/up interleave (EPI=0): combined row j -> n=((j>>5)<<4)|(j&15),
// gu=(j>>4)&1 -> a wave's nt pairs (2p,2p+1) hold (gate,up) of the SAME n.
// XCD swizzle: bijective remap + 4-wide M supertile (verified -34% FETCH).
// ---------------------------------------------------------------------------
template<int EPI>
__global__ __launch_bounds__(512) void gemm8p(
    const f16* __restrict__ Ag,    // (M, SK)
    const int* __restrict__ qwG, const float* __restrict__ scG, const int* __restrict__ qzG,
    const int* __restrict__ qwU, const float* __restrict__ scU, const int* __restrict__ qzU,
    void*      __restrict__ Cv,
    const int SK, const int NT)
{
    __shared__ __align__(16) f16 LA[2][2][128 * 64];  // [dbuf][m-half] 64 KB
    __shared__ __align__(16) f16 LB[2][2][128 * 64];  // [dbuf][n-half] 64 KB

    const int tid  = threadIdx.x;
    const int lane = tid & 63;
    const int wave = tid >> 6;
    const int wm   = wave >> 2;          // A (M) half owned by this wave
    const int wbh  = (wave >> 1) & 1;    // B (N) half
    const int wnq  = wave & 1;           // 64-col quarter within B half
    const int quad = lane >> 4;
    const int lr   = lane & 15;

    // ---- XCD swizzle: bijective gather + 4-wide M-supertile decode ----
    const int GX  = gridDim.x, GY = gridDim.y;
    const int nwg = GX * GY;
    const int lin = blockIdx.y * GX + blockIdx.x;      // HW dispatch order
    const int q8  = nwg >> 3, r8 = nwg & 7;
    const int xcd = lin & 7, ldx = lin >> 3;
    const int s   = (xcd < r8 ? xcd * (q8 + 1)
                              : r8 * (q8 + 1) + (xcd - r8) * q8) + ldx;
    const int span = 4 * GY;                           // GX==16, 16%4==0
    const int mb   = (s / span) * 4 + (s & 3);
    const int cb   = (s % span) >> 2;

    const int m0  = mb * 256;
    const int nb0 = cb * 256;            // B-row (output col) base

    // ---- A staging (global_load_lds, inverse-swizzled source) ----
    const int trow = tid >> 3;                    // 0..63 (r adds 64)
    const int tch  = (tid & 7) ^ (trow & 7);
    const size_t arow = (size_t)(m0 + trow) * SK + (size_t)tch * 8;
    const int lstg = wave * 512;                  // + r*4096 elems

    // ---- B fused-dequant constants ----
    const int RS  = (EPI == 0) ? NN : K;          // qweight/scale row stride
    const int brL = tid & 127;                    // LDS row within half
    const int bk8 = tid >> 7;                     // chunks bk8, bk8+4
    const int*   qwp[2]; const float* scp[2]; const int* qzp[2];
    size_t qoff[2], soff[2], zoff[2]; int zsh[2];
#pragma unroll
    for (int h = 0; h < 2; ++h) {
        int j = nb0 + h * 128 + brL;
        int nc;
        if constexpr (EPI == 0) {
            nc = ((j >> 5) << 4) | (j & 15);
            int gu = (j >> 4) & 1;
            qwp[h] = gu ? qwU : qwG;
            scp[h] = gu ? scU : scG;
            qzp[h] = gu ? qzU : qzG;
        } else {
            nc = j; qwp[h] = qwG; scp[h] = scG; qzp[h] = qzG;
        }
        qoff[h] = (size_t)bk8 * RS + nc;
        soff[h] = nc;
        zoff[h] = nc >> 3;
        zsh[h]  = (nc & 7) * 4;
    }

    // frag-read chunk offsets (elems), swizzle applied: chunk ^ (row&7)
    const int c0e = ((quad) ^ (lr & 7)) * 8;
    const int c1e = ((4 + quad) ^ (lr & 7)) * 8;

    f32x4 acc[8][4];
#pragma unroll
    for (int i = 0; i < 8; ++i)
#pragma unroll
        for (int j = 0; j < 4; ++j) acc[i][j] = (f32x4){0.f, 0.f, 0.f, 0.f};

    f16x8 a_[2][4];        // [kk][mt]  current quadrant-row of A
    f16x8 b_[2][2][2];     // [nh][kk][n2]
    unsigned qr[2][2]; float scr[2]; unsigned zr[2]; f16x8 bval[2][2];

#define STAGE_A(D_, H_, T_) do {                                              \
    const f16* s_ = Ag + arow + (size_t)(H_) * 128 * SK + (size_t)(T_) * 64;  \
    gll16(s_, &LA[D_][H_][lstg]);                                             \
    gll16(s_ + (size_t)64 * SK, &LA[D_][H_][4096 + lstg]); } while (0)

#define ISSUEB(T_) do {                                                       \
    _Pragma("unroll")                                                         \
    for (int h = 0; h < 2; ++h) {                                             \
        qr[h][0] = (unsigned)qwp[h][(size_t)((T_) * 8) * RS + qoff[h]];       \
        qr[h][1] = (unsigned)qwp[h][(size_t)((T_) * 8 + 4) * RS + qoff[h]];   \
        scr[h]   = scp[h][(size_t)((T_) >> 1) * RS + soff[h]];                \
        zr[h]    = (unsigned)qzp[h][(size_t)((T_) >> 1) * (RS >> 3) + zoff[h]]; \
    } } while (0)

#define DQB() do {                                                            \
    _Pragma("unroll")                                                         \
    for (int h = 0; h < 2; ++h) {                                             \
        f16 sh_ = (f16)scr[h];                                                \
        f16 zc_ = (f16)(float)(1025 + (int)((zr[h] >> zsh[h]) & 15u));        \
        f16x2 s2_ = {sh_, sh_}, zc2_ = {zc_, zc_};                            \
        bval[h][0] = dq8(qr[h][0], s2_, zc2_);                                \
        bval[h][1] = dq8(qr[h][1], s2_, zc2_);                                \
    } } while (0)

#define WRITEB(D_) do {                                                       \
    _Pragma("unroll")                                                         \
    for (int h = 0; h < 2; ++h) {                                             \
        *(f16x8*)&LB[D_][h][brL * 64 + ((bk8 ^ (brL & 7)) * 8)]       = bval[h][0]; \
        *(f16x8*)&LB[D_][h][brL * 64 + (((bk8 + 4) ^ (brL & 7)) * 8)] = bval[h][1]; \
    } } while (0)

#define LOAD_A(D_, MH_) do {                                                  \
    _Pragma("unroll")                                                         \
    for (int mt = 0; mt < 4; ++mt) {                                          \
        a_[0][mt] = *(const f16x8*)&LA[D_][wm][((MH_) * 64 + mt * 16 + lr) * 64 + c0e]; \
        a_[1][mt] = *(const f16x8*)&LA[D_][wm][((MH_) * 64 + mt * 16 + lr) * 64 + c1e]; \
    } } while (0)

#define LOAD_B(D_, NH_) do {                                                  \
    _Pragma("unroll")                                                         \
    for (int n2 = 0; n2 < 2; ++n2) {                                          \
        b_[NH_][0][n2] = *(const f16x8*)&LB[D_][wbh][(wnq * 64 + (NH_) * 32 + n2 * 16 + lr) * 64 + c0e]; \
        b_[NH_][1][n2] = *(const f16x8*)&LB[D_][wbh][(wnq * 64 + (NH_) * 32 + n2 * 16 + lr) * 64 + c1e]; \
    } } while (0)

#define QMFMA(MH_, NH_) do {                                                  \
    __builtin_amdgcn_s_setprio(1);                                            \
    _Pragma("unroll")                                                         \
    for (int kk = 0; kk < 2; ++kk)                                            \
    _Pragma("unroll")                                                         \
    for (int n2 = 0; n2 < 2; ++n2)                                            \
    _Pragma("unroll")                                                         \
    for (int mt = 0; mt < 4; ++mt)                                            \
        acc[(MH_) * 4 + mt][(NH_) * 2 + n2] =                                 \
            __builtin_amdgcn_mfma_f32_16x16x32_f16(                           \
                a_[kk][mt], b_[NH_][kk][n2],                                  \
                acc[(MH_) * 4 + mt][(NH_) * 2 + n2], 0, 0, 0);                \
    __builtin_amdgcn_s_setprio(0); } while (0)

#define BAR() do { __builtin_amdgcn_s_barrier();                              \
                   __builtin_amdgcn_sched_barrier(0); } while (0)
#define LGKM0() do { asm volatile("s_waitcnt lgkmcnt(0)" ::: "memory");       \
                     __builtin_amdgcn_sched_barrier(0); } while (0)
#define WAITV0() do { asm volatile("s_waitcnt vmcnt(0)" ::: "memory");        \
                      __builtin_amdgcn_sched_barrier(0); } while (0)

    // prologue: B tiles 0,1 dequanted+written; A tiles 0,1 staged; drain.
    ISSUEB(0); DQB(); WRITEB(0);
    ISSUEB(1); DQB(); WRITEB(1);
    STAGE_A(0, 0, 0); STAGE_A(0, 1, 0);
    STAGE_A(1, 0, 1); STAGE_A(1, 1, 1);
    LGKM0(); WAITV0(); BAR();

#pragma unroll 2
    for (int t = 0; t < NT; ++t) {
        const int d  = t & 1;
        const bool s2 = (t + 2 < NT);

        // P0
        if (s2) ISSUEB(t + 2);
        LOAD_A(d, 0);
        LOAD_B(d, 0);
        QMFMA(0, 0);
        BAR();
        // P1
        LOAD_B(d, 1);
        QMFMA(0, 1);
        BAR();
        // P2
        LOAD_A(d, 1);
        if (s2) DQB();            // compiler vmcnt wait: all drained loads >=1 tile old
        QMFMA(1, 0);
        BAR();
        // P3
        if (s2) { WRITEB(d); STAGE_A(d, 0, t + 2); STAGE_A(d, 1, t + 2); }
        QMFMA(1, 1);
        if (s2) { LGKM0(); }
        else if (t + 1 < NT) { WAITV0(); }
        BAR();
    }

    if constexpr (EPI == 0) {
        // silu(g)*u -> h fp16; nt pairs (2p, 2p+1) = (gate, up) of same n.
        f16* __restrict__ h = (f16*)Cv;
        const int jw = nb0 + wbh * 128 + wnq * 64;   // global combined col
#pragma unroll
        for (int p = 0; p < 2; ++p) {
            const int nbase = ((jw + p * 32) >> 5) * 16;
            const int n  = nbase + lr;
            const int np = (n & ~7) | (((n & 3) << 1) | ((n >> 2) & 1));
#pragma unroll
            for (int mt8 = 0; mt8 < 8; ++mt8)
#pragma unroll
                for (int r = 0; r < 4; ++r) {
                    const int m = m0 + wm * 128 + mt8 * 16 + quad * 4 + r;
                    float gv = acc[mt8][2 * p][r];
                    float uv = acc[mt8][2 * p + 1][r];
                    float hv = (gv / (1.0f + __expf(-gv))) * uv;
                    h[(size_t)m * NN + np] = (f16)hv;
                }
        }
    } else {
        float* __restrict__ out = (float*)Cv;
        const int cw = nb0 + wbh * 128 + wnq * 64;
#pragma unroll
        for (int nt = 0; nt < 4; ++nt)
#pragma unroll
            for (int mt8 = 0; mt8 < 8; ++mt8)
#pragma unroll
                for (int r = 0; r < 4; ++r) {
                    const int m = m0 + wm * 128 + mt8 * 16 + quad * 4 + r;
                    out[(size_t)m * K + cw + nt * 16 + lr] = acc[mt8][nt][r];
                }
    }

#undef STAGE_A
#undef ISSUEB
#undef DQB
#undef WRITEB
#undef LOAD_A
#undef LOAD_B
#undef QMFMA
#undef BAR
#undef LGKM0
#undef WAITV0
}

extern "C" void kernel_launch(void* const* d_in, const int* in_sizes, int n_in,
                              void* d_out, int out_size, void* d_ws, size_t ws_size,
                              hipStream_t stream) {
    const float* x   = (const float*)d_in[0];
    const int*   gqw = (const int*)d_in[1];
    const float* gsc = (const float*)d_in[2];
    const int*   gqz = (const int*)d_in[3];
    const int*   uqw = (const int*)d_in[4];
    const float* usc = (const float*)d_in[5];
    const int*   uqz = (const int*)d_in[6];
    const int*   dqw = (const int*)d_in[7];
    const float* dsc = (const float*)d_in[8];
    const int*   dqz = (const int*)d_in[9];
    float* out = (float*)d_out;

    const size_t HB = (size_t)M * NN * 2;   // h: 90,177,536 B
    char* ws = (char*)d_ws;
    f16* h  = (f16*)ws;
    f16* xp = (f16*)(ws + HB);              // +33.5 MB (fits, verified prev)

    convert_x_kernel<<<(M * K / 8) / 256, 256, 0, stream>>>(x, xp);

    // gate/up fused-dequant GEMM: one dispatch, grid 16 x 86 (nwg%8==0).
    gemm8p<0><<<dim3(M / 256, (2 * NN) / 256), 512, 0, stream>>>(
        xp, gqw, gsc, gqz, uqw, usc, uqz, (void*)h, K, K / 64);

    // down fused-dequant GEMM: one dispatch, grid 16 x 16.
    gemm8p<1><<<dim3(M / 256, K / 256), 512, 0, stream>>>(
        h, dqw, dsc, dqz, dqw, dsc, dqz, (void*)out, NN, NN / 64);
}